// Round 1
// baseline (1145.158 us; speedup 1.0000x reference)
//
#include <hip/hip_runtime.h>

#define NN 50000
#define NE 800000
#define NG 512
#define F0 92
#define FF 64
#define NB 41
#define HH 128

__device__ __forceinline__ float softplusf(float x) {
    return fmaxf(x, 0.f) + __logf(1.f + __expf(-fabsf(x)));
}
__device__ __forceinline__ float sigmoidf(float x) {
    return __fdividef(1.f, 1.f + __expf(-x));
}

// h = x @ embW + embb   (one wave per node, W columns in registers)
__global__ __launch_bounds__(256) void emb_kernel(
    const float* __restrict__ x, const float* __restrict__ W,
    const float* __restrict__ bias, float* __restrict__ h)
{
    __shared__ float sx[4][F0];                 // 368 B rows (16B multiple)
    const int lane = threadIdx.x & 63;
    const int w = threadIdx.x >> 6;
    float wr[F0];
#pragma unroll
    for (int k = 0; k < F0; ++k) wr[k] = W[k * FF + lane];
    const float bv = bias[lane];
    const int nit = NN / 4;                     // NN divisible by 4
    for (int it = blockIdx.x; it < nit; it += gridDim.x) {
        const int n = it * 4 + w;
        if (lane < 46) {                        // 92 floats, 2 per lane
            sx[w][lane * 2]     = x[n * F0 + lane * 2];
            sx[w][lane * 2 + 1] = x[n * F0 + lane * 2 + 1];
        }
        __syncthreads();
        float acc = bv;
#pragma unroll
        for (int k4 = 0; k4 < F0 / 4; ++k4) {
            float4 q = *(const float4*)&sx[w][k4 * 4];
            acc = fmaf(q.x, wr[k4 * 4 + 0], acc);
            acc = fmaf(q.y, wr[k4 * 4 + 1], acc);
            acc = fmaf(q.z, wr[k4 * 4 + 2], acc);
            acc = fmaf(q.w, wr[k4 * 4 + 3], acc);
        }
        h[n * FF + lane] = acc;
        __syncthreads();
    }
}

// column sums / sumsq of src[N,64] -> stats[0:64]=sum, stats[64:128]=sumsq
__global__ __launch_bounds__(256) void stats_kernel(
    const float* __restrict__ src, float* __restrict__ stats)
{
    __shared__ float sd[2][4][FF];
    const int f = threadIdx.x & 63;
    const int r = threadIdx.x >> 6;
    float s = 0.f, s2 = 0.f;
    for (int n = blockIdx.x * 4 + r; n < NN; n += gridDim.x * 4) {
        float v = src[n * FF + f];
        s += v;
        s2 = fmaf(v, v, s2);
    }
    sd[0][r][f] = s;
    sd[1][r][f] = s2;
    __syncthreads();
    if (threadIdx.x < FF) {
        float ts = sd[0][0][f] + sd[0][1][f] + sd[0][2][f] + sd[0][3][f];
        float t2 = sd[1][0][f] + sd[1][1][f] + sd[1][2][f] + sd[1][3][f];
        atomicAdd(&stats[f], ts);
        atomicAdd(&stats[FF + f], t2);
    }
}

// stats[128:192]=A=rstd*gamma, stats[192:256]=B=beta-mean*A
__global__ void finalize_kernel(const float* __restrict__ g, const float* __restrict__ b,
                                float* __restrict__ stats)
{
    const int f = threadIdx.x;
    const float inv = 1.f / (float)NN;
    float mean = stats[f] * inv;
    float var = stats[FF + f] * inv - mean * mean;
    float rstd = rsqrtf(var + 1e-5f);
    float A = rstd * g[f];
    stats[2 * FF + f] = A;
    stats[3 * FF + f] = fmaf(-mean, A, b[f]);
}

// xn = bn1(h); four projection planes xn@W (wave w owns one 64x64 matrix in regs)
__global__ __launch_bounds__(256) void node_kernel(
    const float* __restrict__ h, const float* __restrict__ stats,
    const float* __restrict__ Wf, const float* __restrict__ Ws,
    float* __restrict__ xn,
    float* __restrict__ pSf, float* __restrict__ pDf,
    float* __restrict__ pSs, float* __restrict__ pDs)
{
    __shared__ float sx[4][FF];                 // 256 B rows
    const int lane = threadIdx.x & 63;
    const int w = threadIdx.x >> 6;
    const float* W = (w < 2) ? Wf : Ws;
    const int rowbase = (w & 1) * FF;           // w0/w2: src rows 0..63, w1/w3: dst rows 64..127
    float wr[FF];
#pragma unroll
    for (int k = 0; k < FF; ++k) wr[k] = W[(rowbase + k) * FF + lane];
    const float A = stats[2 * FF + lane];
    const float B = stats[3 * FF + lane];
    float* outp = (w == 0) ? pSf : (w == 1) ? pDf : (w == 2) ? pSs : pDs;
    for (int n = blockIdx.x; n < NN; n += gridDim.x) {
        const float xv = fmaf(h[n * FF + lane], A, B);
        if (w == 0) xn[n * FF + lane] = xv;
        sx[w][lane] = xv;
        __syncthreads();
        float acc = 0.f;
#pragma unroll
        for (int k4 = 0; k4 < FF / 4; ++k4) {
            float4 q = *(const float4*)&sx[w][k4 * 4];
            acc = fmaf(q.x, wr[k4 * 4 + 0], acc);
            acc = fmaf(q.y, wr[k4 * 4 + 1], acc);
            acc = fmaf(q.z, wr[k4 * 4 + 2], acc);
            acc = fmaf(q.w, wr[k4 * 4 + 3], acc);
        }
        outp[n * FF + lane] = acc;
        __syncthreads();
    }
}

// per-edge: gate = sigmoid(gSf+gDf+ea@WfE+bf), core = softplus(gSs+gDs+ea@WsE+bs)
// agg[src] += gate*core   (wave per edge, lane = feature, WE columns in regs)
__global__ __launch_bounds__(256) void edge_kernel(
    const int* __restrict__ ei, const float* __restrict__ ea,
    const float* __restrict__ Wf, const float* __restrict__ Ws,
    const float* __restrict__ bf, const float* __restrict__ bs,
    const float* __restrict__ pSf, const float* __restrict__ pDf,
    const float* __restrict__ pSs, const float* __restrict__ pDs,
    float* __restrict__ agg)
{
    __shared__ float sea[4][44];                // 176 B rows (16B multiple)
    const int lane = threadIdx.x & 63;
    const int w = threadIdx.x >> 6;
    float wfr[44], wsr[44];
#pragma unroll
    for (int k = 0; k < 44; ++k) {
        wfr[k] = (k < NB) ? Wf[(2 * FF + k) * FF + lane] : 0.f;
        wsr[k] = (k < NB) ? Ws[(2 * FF + k) * FF + lane] : 0.f;
    }
    const float bfv = bf[lane], bsv = bs[lane];
    const int nit = NE / 4;                     // NE divisible by 4
    for (int it = blockIdx.x; it < nit; it += gridDim.x) {
        const int e = it * 4 + w;
        const int src = ei[e];
        const int dst = ei[NE + e];
        const float gSf = pSf[src * FF + lane];
        const float gDf = pDf[dst * FF + lane];
        const float gSs = pSs[src * FF + lane];
        const float gDs = pDs[dst * FF + lane];
        float v = 0.f;
        if (lane < NB) v = ea[(size_t)e * NB + lane];
        if (lane < 44) sea[w][lane] = v;        // pad lanes 41..43 with 0
        __syncthreads();
        float accF = bfv, accS = bsv;
#pragma unroll
        for (int k4 = 0; k4 < 11; ++k4) {
            float4 q = *(const float4*)&sea[w][k4 * 4];
            accF = fmaf(q.x, wfr[k4 * 4 + 0], accF); accS = fmaf(q.x, wsr[k4 * 4 + 0], accS);
            accF = fmaf(q.y, wfr[k4 * 4 + 1], accF); accS = fmaf(q.y, wsr[k4 * 4 + 1], accS);
            accF = fmaf(q.z, wfr[k4 * 4 + 2], accF); accS = fmaf(q.z, wsr[k4 * 4 + 2], accS);
            accF = fmaf(q.w, wfr[k4 * 4 + 3], accF); accS = fmaf(q.w, wsr[k4 * 4 + 3], accS);
        }
        const float m = sigmoidf(accF + gSf + gDf) * softplusf(accS + gSs + gDs);
        unsafeAtomicAdd(&agg[src * FF + lane], m);
    }
}

// h = softplus(bn2(agg) + xn); last conv also accumulates the per-graph pool
__global__ __launch_bounds__(256) void update_kernel(
    const float* __restrict__ agg, const float* __restrict__ xn,
    const float* __restrict__ stats, float* __restrict__ h,
    const int* __restrict__ batch, float* __restrict__ pool,
    float* __restrict__ pcnt, const int do_pool)
{
    const int total = NN * FF;
    for (int idx = blockIdx.x * blockDim.x + threadIdx.x; idx < total;
         idx += gridDim.x * blockDim.x) {
        const int f = idx & 63;
        const int n = idx >> 6;
        const float A = stats[2 * FF + f];
        const float B = stats[3 * FF + f];
        const float v = softplusf(fmaf(agg[idx], A, B) + xn[idx]);
        if (do_pool) {
            const int g = batch[n];
            unsafeAtomicAdd(&pool[g * FF + f], v);
            if (f == 0) unsafeAtomicAdd(&pcnt[g], 1.f);
        } else {
            h[idx] = v;
        }
    }
}

// crys = softplus(softplus(pool/cnt) @ fc1 + b1); out = crys @ outW + outb
__global__ __launch_bounds__(128) void readout_kernel(
    const float* __restrict__ pool, const float* __restrict__ pcnt,
    const float* __restrict__ fc1W, const float* __restrict__ fc1b,
    const float* __restrict__ outW, const float* __restrict__ outb,
    float* __restrict__ out)
{
    __shared__ float sp[FF];
    __shared__ float red[2];
    const int g = blockIdx.x;
    const int t = threadIdx.x;
    if (t < FF) {
        const float c = fmaxf(pcnt[g], 1.f);
        sp[t] = softplusf(pool[g * FF + t] / c);
    }
    __syncthreads();
    float a = fc1b[t];
#pragma unroll
    for (int k = 0; k < FF; ++k) a = fmaf(sp[k], fc1W[k * HH + t], a);
    float o = softplusf(a) * outW[t];
#pragma unroll
    for (int off = 32; off > 0; off >>= 1) o += __shfl_down(o, off, 64);
    if ((t & 63) == 0) red[t >> 6] = o;
    __syncthreads();
    if (t == 0) out[g] = red[0] + red[1] + outb[0];
}

extern "C" void kernel_launch(void* const* d_in, const int* in_sizes, int n_in,
                              void* d_out, int out_size, void* d_ws, size_t ws_size,
                              hipStream_t stream)
{
    const float* x     = (const float*)d_in[0];
    const int*   ei    = (const int*)  d_in[1];
    const float* ea    = (const float*)d_in[2];
    const int*   batch = (const int*)  d_in[3];
    const float* embW  = (const float*)d_in[4];
    const float* embb  = (const float*)d_in[5];
    const float* bn1g  = (const float*)d_in[6];
    const float* bn1b  = (const float*)d_in[7];
    const float* bn2g  = (const float*)d_in[8];
    const float* bn2b  = (const float*)d_in[9];
    const float* lnfW  = (const float*)d_in[10];
    const float* lnfb  = (const float*)d_in[11];
    const float* lnsW  = (const float*)d_in[12];
    const float* lnsb  = (const float*)d_in[13];
    const float* fc1W  = (const float*)d_in[14];
    const float* fc1b  = (const float*)d_in[15];
    const float* outW  = (const float*)d_in[16];
    const float* outb  = (const float*)d_in[17];

    float* ws    = (float*)d_ws;
    float* h     = ws;
    float* xn    = h    + (size_t)NN * FF;
    float* pSf   = xn   + (size_t)NN * FF;
    float* pDf   = pSf  + (size_t)NN * FF;
    float* pSs   = pDf  + (size_t)NN * FF;
    float* pDs   = pSs  + (size_t)NN * FF;
    float* agg   = pDs  + (size_t)NN * FF;
    float* stats = agg  + (size_t)NN * FF;
    float* pool  = stats + 4 * FF;
    float* pcnt  = pool + (size_t)NG * FF;

    hipMemsetAsync(pool, 0, (NG * FF + NG) * sizeof(float), stream);
    emb_kernel<<<1024, 256, 0, stream>>>(x, embW, embb, h);

    for (int i = 0; i < 3; ++i) {
        const float* Wf  = lnfW + (size_t)i * 169 * FF;
        const float* Wsp = lnsW + (size_t)i * 169 * FF;
        hipMemsetAsync(stats, 0, 2 * FF * sizeof(float), stream);
        stats_kernel<<<256, 256, 0, stream>>>(h, stats);
        finalize_kernel<<<1, 64, 0, stream>>>(bn1g + i * FF, bn1b + i * FF, stats);
        node_kernel<<<1024, 256, 0, stream>>>(h, stats, Wf, Wsp, xn, pSf, pDf, pSs, pDs);
        hipMemsetAsync(agg, 0, (size_t)NN * FF * sizeof(float), stream);
        edge_kernel<<<2048, 256, 0, stream>>>(ei, ea, Wf, Wsp, lnfb + i * FF, lnsb + i * FF,
                                              pSf, pDf, pSs, pDs, agg);
        hipMemsetAsync(stats, 0, 2 * FF * sizeof(float), stream);
        stats_kernel<<<256, 256, 0, stream>>>(agg, stats);
        finalize_kernel<<<1, 64, 0, stream>>>(bn2g + i * FF, bn2b + i * FF, stats);
        update_kernel<<<2048, 256, 0, stream>>>(agg, xn, stats, h, batch, pool, pcnt,
                                                (i == 2) ? 1 : 0);
    }
    readout_kernel<<<NG, HH, 0, stream>>>(pool, pcnt, fc1W, fc1b, outW, outb, (float*)d_out);
}

// Round 2
// 1071.261 us; speedup vs baseline: 1.0690x; 1.0690x over previous
//
#include <hip/hip_runtime.h>

#define NN 50000
#define NE 800000
#define NG 512
#define F0 92
#define FF 64
#define NB 41
#define HH 128

typedef float f4u __attribute__((ext_vector_type(4), aligned(4)));

__device__ __forceinline__ float softplusf(float x) {
    return fmaxf(x, 0.f) + __logf(1.f + __expf(-fabsf(x)));
}
__device__ __forceinline__ float sigmoidf(float x) {
    return __fdividef(1.f, 1.f + __expf(-x));
}

// h = x @ embW + embb   (one wave per node, W columns in registers)
__global__ __launch_bounds__(256, 4) void emb_kernel(
    const float* __restrict__ x, const float* __restrict__ W,
    const float* __restrict__ bias, float* __restrict__ h)
{
    __shared__ float sx[4][F0];
    const int lane = threadIdx.x & 63;
    const int w = threadIdx.x >> 6;
    float wr[F0];
#pragma unroll
    for (int k = 0; k < F0; ++k) wr[k] = W[k * FF + lane];
    const float bv = bias[lane];
    const int nit = NN / 4;
    for (int it = blockIdx.x; it < nit; it += gridDim.x) {
        const int n = it * 4 + w;
        if (lane < 46) {
            sx[w][lane * 2]     = x[n * F0 + lane * 2];
            sx[w][lane * 2 + 1] = x[n * F0 + lane * 2 + 1];
        }
        __syncthreads();
        float acc = bv;
#pragma unroll
        for (int k4 = 0; k4 < F0 / 4; ++k4) {
            float4 q = *(const float4*)&sx[w][k4 * 4];
            acc = fmaf(q.x, wr[k4 * 4 + 0], acc);
            acc = fmaf(q.y, wr[k4 * 4 + 1], acc);
            acc = fmaf(q.z, wr[k4 * 4 + 2], acc);
            acc = fmaf(q.w, wr[k4 * 4 + 3], acc);
        }
        h[n * FF + lane] = acc;
        __syncthreads();
    }
}

// column sums / sumsq of src[N,64] -> stats[0:64]=sum, stats[64:128]=sumsq
__global__ __launch_bounds__(256) void stats_kernel(
    const float* __restrict__ src, float* __restrict__ stats)
{
    __shared__ float sd[2][4][FF];
    const int f = threadIdx.x & 63;
    const int r = threadIdx.x >> 6;
    float s = 0.f, s2 = 0.f;
    for (int n = blockIdx.x * 4 + r; n < NN; n += gridDim.x * 4) {
        float v = src[n * FF + f];
        s += v;
        s2 = fmaf(v, v, s2);
    }
    sd[0][r][f] = s;
    sd[1][r][f] = s2;
    __syncthreads();
    if (threadIdx.x < FF) {
        float ts = sd[0][0][f] + sd[0][1][f] + sd[0][2][f] + sd[0][3][f];
        float t2 = sd[1][0][f] + sd[1][1][f] + sd[1][2][f] + sd[1][3][f];
        atomicAdd(&stats[f], ts);
        atomicAdd(&stats[FF + f], t2);
    }
}

// stats[128:192]=A=rstd*gamma, stats[192:256]=B=beta-mean*A
__global__ void finalize_kernel(const float* __restrict__ g, const float* __restrict__ b,
                                float* __restrict__ stats)
{
    const int f = threadIdx.x;
    const float inv = 1.f / (float)NN;
    float mean = stats[f] * inv;
    float var = stats[FF + f] * inv - mean * mean;
    float rstd = rsqrtf(var + 1e-5f);
    float A = rstd * g[f];
    stats[2 * FF + f] = A;
    stats[3 * FF + f] = fmaf(-mean, A, b[f]);
}

// xn = bn1(h); projection planes, interleaved layout:
// pS[n*128 + 2*lane + 0] = (xn@Wf_src)[n,lane] + bf[lane]
// pS[n*128 + 2*lane + 1] = (xn@Ws_src)[n,lane] + bs[lane]
// pD[n*128 + 2*lane + 0] = (xn@Wf_dst)[n,lane]
// pD[n*128 + 2*lane + 1] = (xn@Ws_dst)[n,lane]
__global__ __launch_bounds__(256, 4) void node_kernel(
    const float* __restrict__ h, const float* __restrict__ stats,
    const float* __restrict__ Wf, const float* __restrict__ Ws,
    const float* __restrict__ bf, const float* __restrict__ bs,
    float* __restrict__ xn, float* __restrict__ pS, float* __restrict__ pD)
{
    __shared__ float sx[4][FF];
    const int lane = threadIdx.x & 63;
    const int w = threadIdx.x >> 6;
    const float* W = (w < 2) ? Wf : Ws;
    const int rowbase = (w & 1) * FF;      // w0/w2: src rows, w1/w3: dst rows
    float wr[FF];
#pragma unroll
    for (int k = 0; k < FF; ++k) wr[k] = W[(rowbase + k) * FF + lane];
    const float A = stats[2 * FF + lane];
    const float B = stats[3 * FF + lane];
    float bias = 0.f;
    if (w == 0) bias = bf[lane];
    if (w == 2) bias = bs[lane];
    float* outp = ((w & 1) ? pD : pS) + ((w >> 1) & 1);   // +1 for the "s" slot
    for (int n = blockIdx.x; n < NN; n += gridDim.x) {
        const float xv = fmaf(h[n * FF + lane], A, B);
        if (w == 0) xn[n * FF + lane] = xv;
        sx[w][lane] = xv;
        __syncthreads();
        float acc = bias;
#pragma unroll
        for (int k4 = 0; k4 < FF / 4; ++k4) {
            float4 q = *(const float4*)&sx[w][k4 * 4];
            acc = fmaf(q.x, wr[k4 * 4 + 0], acc);
            acc = fmaf(q.y, wr[k4 * 4 + 1], acc);
            acc = fmaf(q.z, wr[k4 * 4 + 2], acc);
            acc = fmaf(q.w, wr[k4 * 4 + 3], acc);
        }
        outp[(size_t)n * 128 + 2 * lane] = acc;
        __syncthreads();
    }
}

// per-edge: gate = sigmoid(pS.x[src]+pD.x[dst]+ea@WfE), core = softplus(pS.y[src]+pD.y[dst]+ea@WsE)
// agg[src] += gate*core.  Wave per edge, lane = feature, W columns in regs, ea via
// wave-uniform broadcast loads (no LDS, no barriers).
__global__ __launch_bounds__(256, 4) void edge_kernel(
    const int* __restrict__ ei, const float* __restrict__ ea,
    const float* __restrict__ Wf, const float* __restrict__ Ws,
    const float* __restrict__ pS, const float* __restrict__ pD,
    float* __restrict__ agg)
{
    const int lane = threadIdx.x & 63;
    const int w = threadIdx.x >> 6;
    float wfr[NB], wsr[NB];
#pragma unroll
    for (int k = 0; k < NB; ++k) {
        wfr[k] = Wf[(2 * FF + k) * FF + lane];
        wsr[k] = Ws[(2 * FF + k) * FF + lane];
    }
    const int nit = NE / 4;
    for (int it = blockIdx.x; it < nit; it += gridDim.x) {
        const int e = __builtin_amdgcn_readfirstlane(it * 4 + w);
        const int src = ei[e];
        const int dst = ei[NE + e];
        const float2 gS = *(const float2*)(pS + (size_t)src * 128 + 2 * lane);
        const float2 gD = *(const float2*)(pD + (size_t)dst * 128 + 2 * lane);
        const float* er = ea + (size_t)e * NB;
        float accF = 0.f, accS = 0.f;
#pragma unroll
        for (int k4 = 0; k4 < 10; ++k4) {
            const f4u q = *(const f4u*)(er + k4 * 4);
            accF = fmaf(q.x, wfr[k4 * 4 + 0], accF); accS = fmaf(q.x, wsr[k4 * 4 + 0], accS);
            accF = fmaf(q.y, wfr[k4 * 4 + 1], accF); accS = fmaf(q.y, wsr[k4 * 4 + 1], accS);
            accF = fmaf(q.z, wfr[k4 * 4 + 2], accF); accS = fmaf(q.z, wsr[k4 * 4 + 2], accS);
            accF = fmaf(q.w, wfr[k4 * 4 + 3], accF); accS = fmaf(q.w, wsr[k4 * 4 + 3], accS);
        }
        const float q40 = er[40];
        accF = fmaf(q40, wfr[40], accF);
        accS = fmaf(q40, wsr[40], accS);
        accF += gS.x + gD.x;
        accS += gS.y + gD.y;
        const float m = sigmoidf(accF) * softplusf(accS);
        unsafeAtomicAdd(&agg[(size_t)src * FF + lane], m);
    }
}

// h = softplus(bn2(agg) + xn); last conv also accumulates the per-graph pool
__global__ __launch_bounds__(256) void update_kernel(
    const float* __restrict__ agg, const float* __restrict__ xn,
    const float* __restrict__ stats, float* __restrict__ h,
    const int* __restrict__ batch, float* __restrict__ pool,
    float* __restrict__ pcnt, const int do_pool)
{
    const int total = NN * FF;
    for (int idx = blockIdx.x * blockDim.x + threadIdx.x; idx < total;
         idx += gridDim.x * blockDim.x) {
        const int f = idx & 63;
        const int n = idx >> 6;
        const float A = stats[2 * FF + f];
        const float B = stats[3 * FF + f];
        const float v = softplusf(fmaf(agg[idx], A, B) + xn[idx]);
        if (do_pool) {
            const int g = batch[n];
            unsafeAtomicAdd(&pool[g * FF + f], v);
            if (f == 0) unsafeAtomicAdd(&pcnt[g], 1.f);
        } else {
            h[idx] = v;
        }
    }
}

// crys = softplus(softplus(pool/cnt) @ fc1 + b1); out = crys @ outW + outb
__global__ __launch_bounds__(128) void readout_kernel(
    const float* __restrict__ pool, const float* __restrict__ pcnt,
    const float* __restrict__ fc1W, const float* __restrict__ fc1b,
    const float* __restrict__ outW, const float* __restrict__ outb,
    float* __restrict__ out)
{
    __shared__ float sp[FF];
    __shared__ float red[2];
    const int g = blockIdx.x;
    const int t = threadIdx.x;
    if (t < FF) {
        const float c = fmaxf(pcnt[g], 1.f);
        sp[t] = softplusf(pool[g * FF + t] / c);
    }
    __syncthreads();
    float a = fc1b[t];
#pragma unroll
    for (int k = 0; k < FF; ++k) a = fmaf(sp[k], fc1W[k * HH + t], a);
    float o = softplusf(a) * outW[t];
#pragma unroll
    for (int off = 32; off > 0; off >>= 1) o += __shfl_down(o, off, 64);
    if ((t & 63) == 0) red[t >> 6] = o;
    __syncthreads();
    if (t == 0) out[g] = red[0] + red[1] + outb[0];
}

extern "C" void kernel_launch(void* const* d_in, const int* in_sizes, int n_in,
                              void* d_out, int out_size, void* d_ws, size_t ws_size,
                              hipStream_t stream)
{
    const float* x     = (const float*)d_in[0];
    const int*   ei    = (const int*)  d_in[1];
    const float* ea    = (const float*)d_in[2];
    const int*   batch = (const int*)  d_in[3];
    const float* embW  = (const float*)d_in[4];
    const float* embb  = (const float*)d_in[5];
    const float* bn1g  = (const float*)d_in[6];
    const float* bn1b  = (const float*)d_in[7];
    const float* bn2g  = (const float*)d_in[8];
    const float* bn2b  = (const float*)d_in[9];
    const float* lnfW  = (const float*)d_in[10];
    const float* lnfb  = (const float*)d_in[11];
    const float* lnsW  = (const float*)d_in[12];
    const float* lnsb  = (const float*)d_in[13];
    const float* fc1W  = (const float*)d_in[14];
    const float* fc1b  = (const float*)d_in[15];
    const float* outW  = (const float*)d_in[16];
    const float* outb  = (const float*)d_in[17];

    float* ws    = (float*)d_ws;
    float* h     = ws;
    float* xn    = h    + (size_t)NN * FF;
    float* pS    = xn   + (size_t)NN * FF;          // [NN][128] interleaved f/s
    float* pD    = pS   + (size_t)NN * 128;         // [NN][128] interleaved f/s
    float* agg   = pD   + (size_t)NN * 128;
    float* stats = agg  + (size_t)NN * FF;
    float* pool  = stats + 4 * FF;
    float* pcnt  = pool + (size_t)NG * FF;

    hipMemsetAsync(pool, 0, (NG * FF + NG) * sizeof(float), stream);
    emb_kernel<<<1024, 256, 0, stream>>>(x, embW, embb, h);

    for (int i = 0; i < 3; ++i) {
        const float* Wf  = lnfW + (size_t)i * 169 * FF;
        const float* Wsp = lnsW + (size_t)i * 169 * FF;
        hipMemsetAsync(stats, 0, 2 * FF * sizeof(float), stream);
        stats_kernel<<<256, 256, 0, stream>>>(h, stats);
        finalize_kernel<<<1, 64, 0, stream>>>(bn1g + i * FF, bn1b + i * FF, stats);
        node_kernel<<<1024, 256, 0, stream>>>(h, stats, Wf, Wsp,
                                              lnfb + i * FF, lnsb + i * FF, xn, pS, pD);
        hipMemsetAsync(agg, 0, (size_t)NN * FF * sizeof(float), stream);
        edge_kernel<<<2048, 256, 0, stream>>>(ei, ea, Wf, Wsp, pS, pD, agg);
        hipMemsetAsync(stats, 0, 2 * FF * sizeof(float), stream);
        stats_kernel<<<256, 256, 0, stream>>>(agg, stats);
        finalize_kernel<<<1, 64, 0, stream>>>(bn2g + i * FF, bn2b + i * FF, stats);
        update_kernel<<<2048, 256, 0, stream>>>(agg, xn, stats, h, batch, pool, pcnt,
                                                (i == 2) ? 1 : 0);
    }
    readout_kernel<<<NG, HH, 0, stream>>>(pool, pcnt, fc1W, fc1b, outW, outb, (float*)d_out);
}